// Round 7
// baseline (360.372 us; speedup 1.0000x reference)
//
#include <hip/hip_runtime.h>
#include <hip/hip_bf16.h>

typedef __attribute__((ext_vector_type(8))) short short8;
typedef __attribute__((ext_vector_type(4))) float floatx4;

#define MFMA16(a, b, c) __builtin_amdgcn_mfma_f32_16x16x32_bf16((a), (b), (c), 0, 0, 0)

// Problem dims (fixed by setup_inputs)
static constexpr int Bb = 32, Nn = 864, Cc = 768, Hh = 12;
static constexpr int Mm = Bb * Nn;      // 27648
static constexpr int KVROWS = 256;      // padded KV rows per batch (216 used)

__device__ __forceinline__ void gload_lds16(const __hip_bfloat16* g, __hip_bfloat16* l) {
    __builtin_amdgcn_global_load_lds((const __attribute__((address_space(1))) void*)g,
                                     (__attribute__((address_space(3))) void*)l, 16, 0, 0);
}

// ---------------- fused prep: x cvt f32->bf16, W transposes+cvt ----------------
static constexpr int CVT_BLKS = (Mm * Cc / 4) / 256;             // 20736
static constexpr int TQKV_BLKS = (3 * Cc / 32) * (Cc / 32);      // 1728
static constexpr int TPROJ_BLKS = (Cc / 32) * (Cc / 32);         // 576

__global__ __launch_bounds__(256) void prep_kernel(const float* __restrict__ x,
                                                   const float* __restrict__ Wqkv,
                                                   const float* __restrict__ Wproj,
                                                   __hip_bfloat16* __restrict__ xb,
                                                   __hip_bfloat16* __restrict__ WqkvT,
                                                   __hip_bfloat16* __restrict__ WprojT) {
    __shared__ float tile[32][33];
    const int bx = blockIdx.x;
    if (bx < CVT_BLKS) {
        const int i = bx * 256 + threadIdx.x;
        const float4 v = ((const float4*)x)[i];
        __hip_bfloat16 o[4] = {__float2bfloat16(v.x), __float2bfloat16(v.y),
                               __float2bfloat16(v.z), __float2bfloat16(v.w)};
        ((uint2*)xb)[i] = *(const uint2*)o;
        return;
    }
    const float* in;
    __hip_bfloat16* out;
    int R, C, bid;
    if (bx < CVT_BLKS + TQKV_BLKS) {
        bid = bx - CVT_BLKS; in = Wqkv; out = WqkvT; R = Cc; C = 3 * Cc;
    } else {
        bid = bx - CVT_BLKS - TQKV_BLKS; in = Wproj; out = WprojT; R = Cc; C = Cc;
    }
    const int c0 = (bid % (C / 32)) * 32, r0 = (bid / (C / 32)) * 32;
    const int tx = threadIdx.x & 31, ty = threadIdx.x >> 5;
#pragma unroll
    for (int i = 0; i < 32; i += 8)
        tile[ty + i][tx] = in[(size_t)(r0 + ty + i) * C + c0 + tx];
    __syncthreads();
#pragma unroll
    for (int i = 0; i < 32; i += 8)
        out[(size_t)(c0 + ty + i) * R + r0 + tx] = __float2bfloat16(tile[tx][ty + i]);
}

// ---------------- fused QKV GEMM (Q full-M; K/V only rows [0,256) per batch) ---
// m97 structure, BK=64 as two BK=32 panels, XCD-bijective swizzle. V-half blocks
// transpose their tile through T[64][136] (two passes, LDS stays 32768 B) and
// store V^T to VTbuf[32][768][256].
// Round-7 fix: __launch_bounds__(256,5) caps VGPR at ~102 (round-6's 124 VGPR
// limited residency to 4 blocks/CU; LDS allows 5). Epilogue-only spill is cheap.
static constexpr int QBLKS = 6 * (Mm / 128);          // 1296
static constexpr int KVBLKS = 12 * (Bb * KVROWS / 128);  // 768
static constexpr int QKV_NWG = QBLKS + KVBLKS;        // 2064, % 8 == 0

__global__ __launch_bounds__(256, 5) void gemm_qkv(const __hip_bfloat16* __restrict__ A,
                                                   const __hip_bfloat16* __restrict__ WqkvT,
                                                   __hip_bfloat16* __restrict__ Qbuf,
                                                   __hip_bfloat16* __restrict__ Kbuf,
                                                   __hip_bfloat16* __restrict__ VTbuf) {
    __shared__ __align__(16) char SMEM[32768];  // As(16K)+Bs(16K) | T[64][136] bf16
    __hip_bfloat16* As = (__hip_bfloat16*)SMEM;
    __hip_bfloat16* Bs = As + 8192;

    const int braw = (int)blockIdx.x;
    const int sid = (braw & 7) * (QKV_NWG / 8) + (braw >> 3);  // bijective

    int arow0, orow0, btrow, ncol0, bb = 0, keybase = 0;
    __hip_bfloat16* Out;
    int Nout;
    bool vmode = false;
    if (sid < QBLKS) {                 // Q: full M, N=768
        const int nt = sid % 6, mt = sid / 6;
        arow0 = mt * 128; orow0 = arow0;
        btrow = nt * 128; ncol0 = nt * 128;
        Out = Qbuf; Nout = Cc;
    } else {                           // K/V: rows [0,256) per batch, N=1536
        const int s = sid - QBLKS;
        const int nt = s % 12, mt = s / 12;
        bb = mt >> 1; keybase = (mt & 1) << 7;
        arow0 = bb * Nn + keybase;
        btrow = Cc + nt * 128;         // WqkvT rows 768..2304
        if (nt < 6) {                  // K half -> Kbuf [32*256][768]
            orow0 = bb * KVROWS + keybase; ncol0 = nt * 128;
            Out = Kbuf; Nout = Cc;
        } else {                       // V half -> transposed epilogue
            vmode = true; ncol0 = (nt - 6) * 128;
            Out = nullptr; Nout = 0; orow0 = 0;
        }
    }

    const int t = threadIdx.x;
    const int lane = t & 63, wave = t >> 6;
    const int wm = (wave >> 1) * 64, wn = (wave & 1) * 64;
    const int ln = lane & 15, quad = lane >> 4;

    floatx4 acc[4][4] = {};

    const int r0 = t >> 2;          // 0..63
    const int cst = (t & 3) * 8;    // 0,8,16,24
    const __hip_bfloat16* Ag = A + (size_t)(arow0 + r0) * Cc + cst;
    const __hip_bfloat16* Bg = WqkvT + (size_t)(btrow + r0) * Cc + cst;
    const size_t rowskip = (size_t)64 * Cc;

    for (int k0 = 0; k0 < Cc; k0 += 64) {
        gload_lds16(Ag + k0,                &As[t * 8]);
        gload_lds16(Ag + k0 + rowskip,      &As[2048 + t * 8]);
        gload_lds16(Ag + k0 + 32,           &As[4096 + t * 8]);
        gload_lds16(Ag + k0 + 32 + rowskip, &As[6144 + t * 8]);
        gload_lds16(Bg + k0,                &Bs[t * 8]);
        gload_lds16(Bg + k0 + rowskip,      &Bs[2048 + t * 8]);
        gload_lds16(Bg + k0 + 32,           &Bs[4096 + t * 8]);
        gload_lds16(Bg + k0 + 32 + rowskip, &Bs[6144 + t * 8]);
        __syncthreads();

#pragma unroll
        for (int s = 0; s < 2; s++) {
            short8 af[4], bfr[4];
#pragma unroll
            for (int i = 0; i < 4; i++)
                af[i] = *(const short8*)&As[s * 4096 + (wm + i * 16 + ln) * 32 + quad * 8];
#pragma unroll
            for (int j = 0; j < 4; j++)
                bfr[j] = *(const short8*)&Bs[s * 4096 + (wn + j * 16 + ln) * 32 + quad * 8];
#pragma unroll
            for (int i = 0; i < 4; i++)
#pragma unroll
                for (int j = 0; j < 4; j++)
                    acc[i][j] = MFMA16(af[i], bfr[j], acc[i][j]);
        }
        __syncthreads();
    }

    if (!vmode) {
        // Normal store. C/D layout: row = quad*4 + r, col = ln (verified m89/m91)
#pragma unroll
        for (int j = 0; j < 4; j++) {
            const int n = ncol0 + wn + j * 16 + ln;
#pragma unroll
            for (int i = 0; i < 4; i++) {
                const int mrow = orow0 + wm + i * 16 + quad * 4;
#pragma unroll
                for (int r = 0; r < 4; r++)
                    Out[(size_t)(mrow + r) * Nout + n] = __float2bfloat16(acc[i][j][r]);
            }
        }
        return;
    }

    // V^T epilogue: acc value (i,j,r) is V[key = keybase + wm+i*16+quad*4+r]
    //                               [dd  = ncol0 + wn+j*16+ln].
    // Two passes of 64 dd-rows each through T[64][136]; pass p written by the
    // waves with wn == p*64, then the block streams 64 rows to VTbuf coalesced.
    __hip_bfloat16* T = (__hip_bfloat16*)SMEM;  // [64][136]
#pragma unroll
    for (int pass = 0; pass < 2; pass++) {
        if ((wave & 1) == pass) {
#pragma unroll
            for (int j = 0; j < 4; j++) {
                const int ddl = j * 16 + ln;              // dd - pass*64
#pragma unroll
                for (int i = 0; i < 4; i++) {
                    const int key = wm + i * 16 + quad * 4;
                    const __hip_bfloat162 lo =
                        __float22bfloat162_rn(make_float2(acc[i][j][0], acc[i][j][1]));
                    const __hip_bfloat162 hi =
                        __float22bfloat162_rn(make_float2(acc[i][j][2], acc[i][j][3]));
                    uint2 pk = make_uint2(*(const unsigned int*)&lo,
                                          *(const unsigned int*)&hi);
                    *(uint2*)&T[ddl * 136 + key] = pk;
                }
            }
        }
        __syncthreads();
#pragma unroll
        for (int it = 0; it < 4; it++) {
            const int ldd = it * 16 + (t >> 4);
            const int kk = (t & 15) * 8;
            const short8 v = *(const short8*)&T[ldd * 136 + kk];
            *(short8*)&VTbuf[(size_t)(bb * Cc + ncol0 + pass * 64 + ldd) * KVROWS +
                             keybase + kk] = v;
        }
        if (pass == 0) __syncthreads();
    }
}

// ---------------- proj GEMM (m97 structure, unchanged) -------------------------
__global__ __launch_bounds__(256) void gemm_proj(const __hip_bfloat16* __restrict__ A,
                                                 const __hip_bfloat16* __restrict__ BT,
                                                 float* __restrict__ Cout,
                                                 const float* __restrict__ bias) {
    __shared__ __align__(16) __hip_bfloat16 As[8192];
    __shared__ __align__(16) __hip_bfloat16 Bs[8192];
    const int gx = (int)gridDim.x;
    const int nwg = gx * (int)gridDim.y;
    const int braw = (int)blockIdx.y * gx + (int)blockIdx.x;
    const int sid = (braw & 7) * (nwg >> 3) + (braw >> 3);
    const int mt = sid / gx, nt = sid - mt * gx;
    const int m0 = mt << 7, n0 = nt * 128;
    const int t = threadIdx.x;
    const int lane = t & 63, wave = t >> 6;
    const int wm = (wave >> 1) * 64, wn = (wave & 1) * 64;
    const int ln = lane & 15, quad = lane >> 4;

    floatx4 acc[4][4] = {};
    const int r0 = t >> 2, cst = (t & 3) * 8;
    const __hip_bfloat16* Ag = A + (size_t)(m0 + r0) * Cc + cst;
    const __hip_bfloat16* Bg = BT + (size_t)(n0 + r0) * Cc + cst;
    const size_t rowskip = (size_t)64 * Cc;

    for (int k0 = 0; k0 < Cc; k0 += 64) {
        gload_lds16(Ag + k0,                &As[t * 8]);
        gload_lds16(Ag + k0 + rowskip,      &As[2048 + t * 8]);
        gload_lds16(Ag + k0 + 32,           &As[4096 + t * 8]);
        gload_lds16(Ag + k0 + 32 + rowskip, &As[6144 + t * 8]);
        gload_lds16(Bg + k0,                &Bs[t * 8]);
        gload_lds16(Bg + k0 + rowskip,      &Bs[2048 + t * 8]);
        gload_lds16(Bg + k0 + 32,           &Bs[4096 + t * 8]);
        gload_lds16(Bg + k0 + 32 + rowskip, &Bs[6144 + t * 8]);
        __syncthreads();
#pragma unroll
        for (int s = 0; s < 2; s++) {
            short8 af[4], bfr[4];
#pragma unroll
            for (int i = 0; i < 4; i++)
                af[i] = *(const short8*)&As[s * 4096 + (wm + i * 16 + ln) * 32 + quad * 8];
#pragma unroll
            for (int j = 0; j < 4; j++)
                bfr[j] = *(const short8*)&Bs[s * 4096 + (wn + j * 16 + ln) * 32 + quad * 8];
#pragma unroll
            for (int i = 0; i < 4; i++)
#pragma unroll
                for (int j = 0; j < 4; j++)
                    acc[i][j] = MFMA16(af[i], bfr[j], acc[i][j]);
        }
        __syncthreads();
    }
#pragma unroll
    for (int j = 0; j < 4; j++) {
        const int n = n0 + wn + j * 16 + ln;
        const float bv = bias[n];
#pragma unroll
        for (int i = 0; i < 4; i++) {
            const int mrow = m0 + wm + i * 16 + quad * 4;
#pragma unroll
            for (int r = 0; r < 4; r++)
                Cout[(size_t)(mrow + r) * Cc + n] = acc[i][j][r] + bv;
        }
    }
}

// ---------------- fused cross attention (round-2 measured design + VTbuf) ------
// S^T = MFMA(K_frag, Q_frag): lane holds S^T[key = ti*16 + quad*4 + r][q = ln].
// K fragments read directly from Kbuf (L2-resident). V^T staged from VTbuf into
// LDS by LINEAR vectorized copy (VTbuf rows are contiguous -> uint4 load +
// ds_write_b128; no scatter). Additive-mod 8-block column swizzle:
//   store col8' = (kb + dd) % NB8, read mirrors it -> ~2-way banks (free),
// at 2 extra VALU per PV fragment. Pad chunks zero-filled (P=0 x NaN-garbage
// LDS would poison the PV MFMA accumulator).
template <int L, int QOFF, int KVOFF, int NQT, int NCH>
__device__ __forceinline__ void attn_part(const __hip_bfloat16* __restrict__ qb,
                                          const __hip_bfloat16* __restrict__ kb,
                                          const __hip_bfloat16* __restrict__ vtb,
                                          __hip_bfloat16* __restrict__ attn,
                                          int qc, int h, int b,
                                          __hip_bfloat16* VTs) {
    constexpr int KPAD = NCH * 32;               // t 160, s 96
    constexpr int NB8 = KPAD / 8;                // t 20,  s 12
    constexpr int VSTR = KPAD + 8;               // t 168, s 104
    const int t = threadIdx.x, lane = t & 63;
    const int ln = lane & 15, quad = lane >> 4;

    const __hip_bfloat16* kbase = kb + (size_t)(b * KVROWS + KVOFF) * Cc + h * 64;
    const __hip_bfloat16* vtbase =
        vtb + (size_t)(b * Cc + h * 64) * KVROWS + KVOFF;

    // stage V^T: 64 dd-rows x NB8 16B-chunks, zero-pad chunks with kb*8 >= L
    // (L % 8 == 0 for both parts, so chunks are fully valid or fully pad).
    for (int c = t; c < 64 * NB8; c += 256) {
        const int dd = c / NB8, kbk = c - dd * NB8;
        const int colp8 = (kbk + dd) % NB8;
        uint4 val = make_uint4(0u, 0u, 0u, 0u);
        if (kbk * 8 < L)
            val = *(const uint4*)(vtbase + (size_t)dd * KVROWS + kbk * 8);
        *(uint4*)&VTs[dd * VSTR + colp8 * 8] = val;
    }
    __syncthreads();

    const int qt = qc * 4 + (t >> 6);
    if (qt >= NQT) return;  // no further barriers below

    const __hip_bfloat16* qrow = qb + (size_t)(b * Nn + QOFF + qt * 16 + ln) * Cc + h * 64;
    const short8 aq0 = *(const short8*)(qrow + quad * 8);
    const short8 aq1 = *(const short8*)(qrow + 32 + quad * 8);

    // per-j dd % NB8 (compile-time j, runtime ln; hoisted out of the ch loop)
    int ddm[4];
#pragma unroll
    for (int j = 0; j < 4; j++) ddm[j] = (j * 16 + ln) % NB8;

    float dsum = 0.0f;
    floatx4 acco[4] = {};
    constexpr float CSC = 0.18033688011112042f;  // 0.125 * log2(e)

#pragma unroll
    for (int ch = 0; ch < NCH; ch++) {
        unsigned int pk[2][2];
#pragma unroll
        for (int ti2 = 0; ti2 < 2; ti2++) {
            const int ti = ch * 2 + ti2;
            if (ti * 16 >= L) {  // fully-invalid tile (compile-time)
                pk[ti2][0] = 0u; pk[ti2][1] = 0u;
                continue;
            }
            const __hip_bfloat16* krow = kbase + (size_t)(ti * 16 + ln) * Cc;
            const short8 k0 = *(const short8*)(krow + quad * 8);
            const short8 k1 = *(const short8*)(krow + 32 + quad * 8);
            floatx4 s = {0.f, 0.f, 0.f, 0.f};
            s = MFMA16(k0, aq0, s);
            s = MFMA16(k1, aq1, s);
            float p[4];
#pragma unroll
            for (int r = 0; r < 4; r++) {
                float e = exp2f(s[r] * CSC);
                if (ti * 16 + 16 > L)                           // partial tile (compile-time)
                    if (ti * 16 + quad * 4 + r >= L) e = 0.0f;  // runtime lane mask
                p[r] = e;
                dsum += e;
            }
            const __hip_bfloat162 lo = __float22bfloat162_rn(make_float2(p[0], p[1]));
            const __hip_bfloat162 hi = __float22bfloat162_rn(make_float2(p[2], p[3]));
            pk[ti2][0] = *(const unsigned int*)&lo;
            pk[ti2][1] = *(const unsigned int*)&hi;
        }
        // Redistribute: target lane (ln, quad) needs tile (quad>>1), keys from
        // source quads 2*(quad&1) and 2*(quad&1)+1 (4 bf16 each).
        const int srcA = ln + ((quad & 1) << 5);
        const int srcB = srcA + 16;
        const unsigned int c0 = (unsigned int)__shfl((int)pk[0][0], srcA);
        const unsigned int c1 = (unsigned int)__shfl((int)pk[0][1], srcA);
        const unsigned int c2 = (unsigned int)__shfl((int)pk[0][0], srcB);
        const unsigned int c3 = (unsigned int)__shfl((int)pk[0][1], srcB);
        const unsigned int d0 = (unsigned int)__shfl((int)pk[1][0], srcA);
        const unsigned int d1 = (unsigned int)__shfl((int)pk[1][1], srcA);
        const unsigned int d2 = (unsigned int)__shfl((int)pk[1][0], srcB);
        const unsigned int d3 = (unsigned int)__shfl((int)pk[1][1], srcB);
        const bool hi2 = quad >= 2;
        union { unsigned int u[4]; short8 v; } pf;
        pf.u[0] = hi2 ? d0 : c0;
        pf.u[1] = hi2 ? d1 : c1;
        pf.u[2] = hi2 ? d2 : c2;
        pf.u[3] = hi2 ? d3 : c3;
        // O^T accumulate: lane holds O^T[dd = j*16 + quad*4 + r][q = ln].
        // V^T fragment: row dd = j*16+ln, key-block kb = ch*4 + quad (swizzled).
#pragma unroll
        for (int j = 0; j < 4; j++) {
            int cb = ch * 4 + quad + ddm[j];
            if (cb >= NB8) cb -= NB8;
            const short8 vt = *(const short8*)&VTs[(j * 16 + ln) * VSTR + cb * 8];
            acco[j] = MFMA16(vt, pf.v, acco[j]);
        }
    }

    // Denominator: per-lane partials cover keys {quad*4+r over all tiles}, col q=ln.
    dsum += __shfl_xor(dsum, 16);
    dsum += __shfl_xor(dsum, 32);
    const float inv = 1.0f / dsum;

    const size_t orow = (size_t)(b * Nn + QOFF + qt * 16 + ln) * Cc + h * 64;
#pragma unroll
    for (int j = 0; j < 4; j++) {
        const __hip_bfloat162 lo =
            __float22bfloat162_rn(make_float2(acco[j][0] * inv, acco[j][1] * inv));
        const __hip_bfloat162 hi =
            __float22bfloat162_rn(make_float2(acco[j][2] * inv, acco[j][3] * inv));
        uint2 o = make_uint2(*(const unsigned int*)&lo, *(const unsigned int*)&hi);
        *(uint2*)&attn[orow + j * 16 + quad * 4] = o;
    }
}

// t-part: qc in [0,5): queries [0,288), kv-rows [72,216), L=144
// s-part: qc in [5,14): queries [288,864), kv-rows [0,72),  L=72
// XCD swizzle: all 14 qc-blocks of an (h,b) on one XCD (K/VT L2 reuse).
__global__ __launch_bounds__(256, 5) void attn_fused(const __hip_bfloat16* __restrict__ qb,
                                                     const __hip_bfloat16* __restrict__ kb,
                                                     const __hip_bfloat16* __restrict__ vtb,
                                                     __hip_bfloat16* __restrict__ attn) {
    __shared__ __align__(16) __hip_bfloat16 VTs[64 * 168];
    constexpr int NB = 14 * 12 * 32;  // 5376, % 8 == 0 -> bijective swizzle
    const int rid = (int)blockIdx.x + 14 * ((int)blockIdx.y + 12 * (int)blockIdx.z);
    const int vid = (rid & 7) * (NB / 8) + (rid >> 3);
    const int qc = vid % 14, g = vid / 14;
    const int h = g % 12, bq = g / 12;
    if (qc < 5)
        attn_part<144, 0, 72, 18, 5>(qb, kb, vtb, attn, qc, h, bq, VTs);
    else
        attn_part<72, 288, 0, 36, 3>(qb, kb, vtb, attn, qc - 5, h, bq, VTs);
}

// ---------------- launch ----------------
extern "C" void kernel_launch(void* const* d_in, const int* in_sizes, int n_in,
                              void* d_out, int out_size, void* d_ws, size_t ws_size,
                              hipStream_t stream) {
    const float* x     = (const float*)d_in[0];
    const float* Wqkv  = (const float*)d_in[1];
    const float* Wproj = (const float*)d_in[2];
    const float* bproj = (const float*)d_in[3];
    float* out = (float*)d_out;

    // workspace layout (bytes):
    //   [0, 42467328)            x_bf16 (27648 x 768)  -- later reused as attn
    //   [42467328, 46006272)     WqkvT  (2304 x 768)
    //   [46006272, 47185920)     WprojT (768 x 768)
    //   [47185920, 89653248)     Qbuf   (27648 x 768)
    //   [89653248, 102236160)    Kbuf   (32 x 256 x 768)
    //   [102236160, 114819072)   VTbuf  (32 x 768 x 256)
    char* ws = (char*)d_ws;
    __hip_bfloat16* xb     = (__hip_bfloat16*)ws;
    __hip_bfloat16* WqkvT  = (__hip_bfloat16*)(ws + 42467328);
    __hip_bfloat16* WprojT = (__hip_bfloat16*)(ws + 46006272);
    __hip_bfloat16* Qbuf   = (__hip_bfloat16*)(ws + 47185920);
    __hip_bfloat16* Kbuf   = (__hip_bfloat16*)(ws + 89653248);
    __hip_bfloat16* VTbuf  = (__hip_bfloat16*)(ws + 102236160);
    __hip_bfloat16* attn   = (__hip_bfloat16*)ws;  // alias xb: x consumed before attention

    prep_kernel<<<CVT_BLKS + TQKV_BLKS + TPROJ_BLKS, 256, 0, stream>>>(x, Wqkv, Wproj, xb,
                                                                       WqkvT, WprojT);
    gemm_qkv<<<QKV_NWG, 256, 0, stream>>>(xb, WqkvT, Qbuf, Kbuf, VTbuf);
    attn_fused<<<dim3(14, Hh, Bb), 256, 0, stream>>>(Qbuf, Kbuf, VTbuf, attn);
    gemm_proj<<<dim3(Cc / 128, Mm / 128), 256, 0, stream>>>(attn, WprojT, out, bproj);
}

// Round 8
// 341.217 us; speedup vs baseline: 1.0561x; 1.0561x over previous
//
#include <hip/hip_runtime.h>
#include <hip/hip_bf16.h>

typedef __attribute__((ext_vector_type(8))) short short8;
typedef __attribute__((ext_vector_type(4))) float floatx4;

#define MFMA16(a, b, c) __builtin_amdgcn_mfma_f32_16x16x32_bf16((a), (b), (c), 0, 0, 0)

// Problem dims (fixed by setup_inputs)
static constexpr int Bb = 32, Nn = 864, Cc = 768, Hh = 12;
static constexpr int Mm = Bb * Nn;      // 27648
static constexpr int NKV = 2 * Cc;      // 1536 (K block then V block)
static constexpr int KVROWS = 256;      // padded KV rows per batch (216 used)

__device__ __forceinline__ void gload_lds16(const __hip_bfloat16* g, __hip_bfloat16* l) {
    __builtin_amdgcn_global_load_lds((const __attribute__((address_space(1))) void*)g,
                                     (__attribute__((address_space(3))) void*)l, 16, 0, 0);
}

// ---------------- fused prep: x cvt f32->bf16, W transposes+cvt ----------------
static constexpr int CVT_BLKS = (Mm * Cc / 4) / 256;             // 20736
static constexpr int TQKV_BLKS = (3 * Cc / 32) * (Cc / 32);      // 1728
static constexpr int TPROJ_BLKS = (Cc / 32) * (Cc / 32);         // 576

__global__ __launch_bounds__(256) void prep_kernel(const float* __restrict__ x,
                                                   const float* __restrict__ Wqkv,
                                                   const float* __restrict__ Wproj,
                                                   __hip_bfloat16* __restrict__ xb,
                                                   __hip_bfloat16* __restrict__ WqkvT,
                                                   __hip_bfloat16* __restrict__ WprojT) {
    __shared__ float tile[32][33];
    const int bx = blockIdx.x;
    if (bx < CVT_BLKS) {
        const int i = bx * 256 + threadIdx.x;
        const float4 v = ((const float4*)x)[i];
        __hip_bfloat16 o[4] = {__float2bfloat16(v.x), __float2bfloat16(v.y),
                               __float2bfloat16(v.z), __float2bfloat16(v.w)};
        ((uint2*)xb)[i] = *(const uint2*)o;
        return;
    }
    const float* in;
    __hip_bfloat16* out;
    int R, C, bid;
    if (bx < CVT_BLKS + TQKV_BLKS) {
        bid = bx - CVT_BLKS; in = Wqkv; out = WqkvT; R = Cc; C = 3 * Cc;
    } else {
        bid = bx - CVT_BLKS - TQKV_BLKS; in = Wproj; out = WprojT; R = Cc; C = Cc;
    }
    const int c0 = (bid % (C / 32)) * 32, r0 = (bid / (C / 32)) * 32;
    const int tx = threadIdx.x & 31, ty = threadIdx.x >> 5;
#pragma unroll
    for (int i = 0; i < 32; i += 8)
        tile[ty + i][tx] = in[(size_t)(r0 + ty + i) * C + c0 + tx];
    __syncthreads();
#pragma unroll
    for (int i = 0; i < 32; i += 8)
        out[(size_t)(c0 + ty + i) * R + r0 + tx] = __float2bfloat16(tile[tx][ty + i]);
}

// ---------------- fused Q+KV GEMM, NO transpose epilogue -----------------------
// m97 structure, BK=64 as two BK=32 panels, XCD-bijective swizzle over 2064
// blocks. Plain epilogue keeps VGPR at the gemm_bt level (~84) -> 5 blocks/CU
// (1280 slots) -> 2064 blocks = 2 occupancy rounds, vs 3 rounds for separate
// Q (1296, 2 rounds) + KV (768, 1 round) launches. Rounds 5-7 lost this win to
// the V^T epilogue's VGPR/LDS cost (4 blocks/CU -> 3 rounds, measured 84-105us).
static constexpr int QBLKS = 6 * (Mm / 128);             // 1296
static constexpr int KVBLKS = 12 * (Bb * KVROWS / 128);  // 768
static constexpr int QKV_NWG = QBLKS + KVBLKS;           // 2064, % 8 == 0

__global__ __launch_bounds__(256) void gemm_qkv2(const __hip_bfloat16* __restrict__ A,
                                                 const __hip_bfloat16* __restrict__ WqkvT,
                                                 __hip_bfloat16* __restrict__ Qbuf,
                                                 __hip_bfloat16* __restrict__ KVbuf) {
    __shared__ __align__(16) __hip_bfloat16 As[8192];  // panel s at s*4096, row*32+col
    __shared__ __align__(16) __hip_bfloat16 Bs[8192];

    const int braw = (int)blockIdx.x;
    const int sid = (braw & 7) * (QKV_NWG / 8) + (braw >> 3);  // bijective

    int arow0, orow0, btrow0, ncol0, Nout;
    __hip_bfloat16* Out;
    if (sid < QBLKS) {                 // Q: full M, N=768
        const int nt = sid % 6, mt = sid / 6;
        arow0 = mt * 128; orow0 = arow0;
        btrow0 = nt * 128; ncol0 = nt * 128;
        Out = Qbuf; Nout = Cc;
    } else {                           // K/V: rows [0,256) per batch, N=1536
        const int s = sid - QBLKS;
        const int nt = s % 12, mt = s / 12;
        const int bb = mt >> 1, keybase = (mt & 1) << 7;
        arow0 = bb * Nn + keybase;     // x rows [b*864, b*864+256)
        orow0 = bb * KVROWS + keybase; // packed per-batch KV rows
        btrow0 = Cc + nt * 128;        // WqkvT rows 768..2304 (K then V)
        ncol0 = nt * 128;
        Out = KVbuf; Nout = NKV;
    }

    const int t = threadIdx.x;
    const int lane = t & 63, wave = t >> 6;
    const int wm = (wave >> 1) * 64, wn = (wave & 1) * 64;
    const int ln = lane & 15, quad = lane >> 4;

    floatx4 acc[4][4] = {};

    const int r0 = t >> 2;          // 0..63
    const int cst = (t & 3) * 8;    // 0,8,16,24
    const __hip_bfloat16* Ag = A + (size_t)(arow0 + r0) * Cc + cst;
    const __hip_bfloat16* Bg = WqkvT + (size_t)(btrow0 + r0) * Cc + cst;
    const size_t rowskip = (size_t)64 * Cc;

    for (int k0 = 0; k0 < Cc; k0 += 64) {
        gload_lds16(Ag + k0,                &As[t * 8]);
        gload_lds16(Ag + k0 + rowskip,      &As[2048 + t * 8]);
        gload_lds16(Ag + k0 + 32,           &As[4096 + t * 8]);
        gload_lds16(Ag + k0 + 32 + rowskip, &As[6144 + t * 8]);
        gload_lds16(Bg + k0,                &Bs[t * 8]);
        gload_lds16(Bg + k0 + rowskip,      &Bs[2048 + t * 8]);
        gload_lds16(Bg + k0 + 32,           &Bs[4096 + t * 8]);
        gload_lds16(Bg + k0 + 32 + rowskip, &Bs[6144 + t * 8]);
        __syncthreads();

#pragma unroll
        for (int s = 0; s < 2; s++) {
            short8 af[4], bfr[4];
#pragma unroll
            for (int i = 0; i < 4; i++)
                af[i] = *(const short8*)&As[s * 4096 + (wm + i * 16 + ln) * 32 + quad * 8];
#pragma unroll
            for (int j = 0; j < 4; j++)
                bfr[j] = *(const short8*)&Bs[s * 4096 + (wn + j * 16 + ln) * 32 + quad * 8];
#pragma unroll
            for (int i = 0; i < 4; i++)
#pragma unroll
                for (int j = 0; j < 4; j++)
                    acc[i][j] = MFMA16(af[i], bfr[j], acc[i][j]);
        }
        __syncthreads();
    }

    // Epilogue. C/D layout: row = quad*4 + r, col = ln (verified m89/m91)
#pragma unroll
    for (int j = 0; j < 4; j++) {
        const int n = ncol0 + wn + j * 16 + ln;
#pragma unroll
        for (int i = 0; i < 4; i++) {
            const int mrow = orow0 + wm + i * 16 + quad * 4;
#pragma unroll
            for (int r = 0; r < 4; r++)
                Out[(size_t)(mrow + r) * Nout + n] = __float2bfloat16(acc[i][j][r]);
        }
    }
}

// ---------------- proj GEMM: C[M x 768] = A[M x 768] * BT^T + bias (f32 out) ---
__global__ __launch_bounds__(256) void gemm_proj(const __hip_bfloat16* __restrict__ A,
                                                 const __hip_bfloat16* __restrict__ BT,
                                                 float* __restrict__ Cout,
                                                 const float* __restrict__ bias) {
    __shared__ __align__(16) __hip_bfloat16 As[8192];
    __shared__ __align__(16) __hip_bfloat16 Bs[8192];
    const int gx = (int)gridDim.x;
    const int nwg = gx * (int)gridDim.y;
    const int braw = (int)blockIdx.y * gx + (int)blockIdx.x;
    const int sid = (braw & 7) * (nwg >> 3) + (braw >> 3);
    const int mt = sid / gx, nt = sid - mt * gx;
    const int m0 = mt << 7, n0 = nt * 128;
    const int t = threadIdx.x;
    const int lane = t & 63, wave = t >> 6;
    const int wm = (wave >> 1) * 64, wn = (wave & 1) * 64;
    const int ln = lane & 15, quad = lane >> 4;

    floatx4 acc[4][4] = {};
    const int r0 = t >> 2, cst = (t & 3) * 8;
    const __hip_bfloat16* Ag = A + (size_t)(m0 + r0) * Cc + cst;
    const __hip_bfloat16* Bg = BT + (size_t)(n0 + r0) * Cc + cst;
    const size_t rowskip = (size_t)64 * Cc;

    for (int k0 = 0; k0 < Cc; k0 += 64) {
        gload_lds16(Ag + k0,                &As[t * 8]);
        gload_lds16(Ag + k0 + rowskip,      &As[2048 + t * 8]);
        gload_lds16(Ag + k0 + 32,           &As[4096 + t * 8]);
        gload_lds16(Ag + k0 + 32 + rowskip, &As[6144 + t * 8]);
        gload_lds16(Bg + k0,                &Bs[t * 8]);
        gload_lds16(Bg + k0 + rowskip,      &Bs[2048 + t * 8]);
        gload_lds16(Bg + k0 + 32,           &Bs[4096 + t * 8]);
        gload_lds16(Bg + k0 + 32 + rowskip, &Bs[6144 + t * 8]);
        __syncthreads();
#pragma unroll
        for (int s = 0; s < 2; s++) {
            short8 af[4], bfr[4];
#pragma unroll
            for (int i = 0; i < 4; i++)
                af[i] = *(const short8*)&As[s * 4096 + (wm + i * 16 + ln) * 32 + quad * 8];
#pragma unroll
            for (int j = 0; j < 4; j++)
                bfr[j] = *(const short8*)&Bs[s * 4096 + (wn + j * 16 + ln) * 32 + quad * 8];
#pragma unroll
            for (int i = 0; i < 4; i++)
#pragma unroll
                for (int j = 0; j < 4; j++)
                    acc[i][j] = MFMA16(af[i], bfr[j], acc[i][j]);
        }
        __syncthreads();
    }
#pragma unroll
    for (int j = 0; j < 4; j++) {
        const int n = n0 + wn + j * 16 + ln;
        const float bv = bias[n];
#pragma unroll
        for (int i = 0; i < 4; i++) {
            const int mrow = m0 + wm + i * 16 + quad * 4;
#pragma unroll
            for (int r = 0; r < 4; r++)
                Cout[(size_t)(mrow + r) * Cc + n] = acc[i][j][r] + bv;
        }
    }
}

// ---------------- fused cross attention (round-2 design, measured 54.8us) ------
// S^T = MFMA(K_frag, Q_frag): lane holds S^T[key = ti*16 + quad*4 + r][q = ln].
// K fragments read DIRECTLY from KVbuf (L2-resident). Only V is LDS-staged
// (transpose needed), with a mod-add bank swizzle:
//   store col' = (key + 8*(dd>>3)) % KPAD, read mirrors the shift.
template <int L, int QOFF, int KVOFF, int NQT, int NCH>
__device__ __forceinline__ void attn_part(const __hip_bfloat16* __restrict__ qb,
                                          const __hip_bfloat16* __restrict__ kv,
                                          __hip_bfloat16* __restrict__ attn,
                                          int qc, int h, int b,
                                          __hip_bfloat16* VTs) {
    constexpr int KPAD = NCH * 32;               // padded key count for PV: t 160, s 96
    constexpr int VSTR = KPAD + 8;               // LDS stride for VT rows
    const int t = threadIdx.x, lane = t & 63, wave = t >> 6;
    const int ln = lane & 15, quad = lane >> 4;
    const __hip_bfloat16 z16 = __float2bfloat16(0.0f);

    const __hip_bfloat16* kbase = kv + (size_t)(b * KVROWS + KVOFF) * NKV + h * 64;
    const __hip_bfloat16* vbase = kbase + Cc;   // V block at column offset 768

    // stage V transposed: VT[dd][key'], keys zero-padded to KPAD, swizzled cols
    for (int c = t; c < KPAD * 8; c += 256) {
        const int key = c >> 3, s8 = c & 7, d0 = s8 * 8;
        const int colp = (key + 8 * s8) % KPAD;   // dd>>3 == s8 for all 8 stores
        if (key < L) {
            uint4 raw = *(const uint4*)(vbase + (size_t)key * NKV + d0);
            const __hip_bfloat16* pv = (const __hip_bfloat16*)&raw;
#pragma unroll
            for (int jj = 0; jj < 8; jj++) VTs[(d0 + jj) * VSTR + colp] = pv[jj];
        } else {
#pragma unroll
            for (int jj = 0; jj < 8; jj++) VTs[(d0 + jj) * VSTR + colp] = z16;
        }
    }
    __syncthreads();

    const int qt = qc * 4 + wave;
    if (qt >= NQT) return;  // no further barriers below

    const __hip_bfloat16* qrow = qb + (size_t)(b * Nn + QOFF + qt * 16 + ln) * Cc + h * 64;
    const short8 aq0 = *(const short8*)(qrow + quad * 8);
    const short8 aq1 = *(const short8*)(qrow + 32 + quad * 8);

    float dsum = 0.0f;
    floatx4 acco[4] = {};
    constexpr float CSC = 0.18033688011112042f;  // 0.125 * log2(e)

#pragma unroll
    for (int ch = 0; ch < NCH; ch++) {
        unsigned int pk[2][2];
#pragma unroll
        for (int ti2 = 0; ti2 < 2; ti2++) {
            const int ti = ch * 2 + ti2;
            if (ti * 16 >= L) {  // fully-invalid tile (compile-time)
                pk[ti2][0] = 0u; pk[ti2][1] = 0u;
                continue;
            }
            const __hip_bfloat16* krow = kbase + (size_t)(ti * 16 + ln) * NKV;
            const short8 k0 = *(const short8*)(krow + quad * 8);
            const short8 k1 = *(const short8*)(krow + 32 + quad * 8);
            floatx4 s = {0.f, 0.f, 0.f, 0.f};
            s = MFMA16(k0, aq0, s);
            s = MFMA16(k1, aq1, s);
            float p[4];
#pragma unroll
            for (int r = 0; r < 4; r++) {
                float e = exp2f(s[r] * CSC);
                if (ti * 16 + 16 > L)                           // partial tile (compile-time)
                    if (ti * 16 + quad * 4 + r >= L) e = 0.0f;  // runtime lane mask
                p[r] = e;
                dsum += e;
            }
            const __hip_bfloat162 lo = __float22bfloat162_rn(make_float2(p[0], p[1]));
            const __hip_bfloat162 hi = __float22bfloat162_rn(make_float2(p[2], p[3]));
            pk[ti2][0] = *(const unsigned int*)&lo;
            pk[ti2][1] = *(const unsigned int*)&hi;
        }
        // Redistribute: target lane (ln, quad) needs tile (quad>>1), keys from
        // source quads 2*(quad&1) and 2*(quad&1)+1 (4 bf16 each).
        const int srcA = ln + ((quad & 1) << 5);
        const int srcB = srcA + 16;
        const unsigned int c0 = (unsigned int)__shfl((int)pk[0][0], srcA);
        const unsigned int c1 = (unsigned int)__shfl((int)pk[0][1], srcA);
        const unsigned int c2 = (unsigned int)__shfl((int)pk[0][0], srcB);
        const unsigned int c3 = (unsigned int)__shfl((int)pk[0][1], srcB);
        const unsigned int d0 = (unsigned int)__shfl((int)pk[1][0], srcA);
        const unsigned int d1 = (unsigned int)__shfl((int)pk[1][1], srcA);
        const unsigned int d2 = (unsigned int)__shfl((int)pk[1][0], srcB);
        const unsigned int d3 = (unsigned int)__shfl((int)pk[1][1], srcB);
        const bool hi2 = quad >= 2;
        union { unsigned int u[4]; short8 v; } pf;
        pf.u[0] = hi2 ? d0 : c0;
        pf.u[1] = hi2 ? d1 : c1;
        pf.u[2] = hi2 ? d2 : c2;
        pf.u[3] = hi2 ? d3 : c3;
        // O^T accumulate: lane holds O^T[dd = j*16 + quad*4 + r][q = ln]
#pragma unroll
        for (int j = 0; j < 4; j++) {
            const int dd = j * 16 + ln;
            const int colp = (ch * 32 + quad * 8 + ((dd >> 3) << 3)) % KPAD;
            const short8 vt = *(const short8*)&VTs[dd * VSTR + colp];
            acco[j] = MFMA16(vt, pf.v, acco[j]);
        }
    }

    // Denominator: per-lane partials cover keys {quad*4+r over all tiles}, col q=ln.
    dsum += __shfl_xor(dsum, 16);
    dsum += __shfl_xor(dsum, 32);
    const float inv = 1.0f / dsum;

    const size_t orow = (size_t)(b * Nn + QOFF + qt * 16 + ln) * Cc + h * 64;
#pragma unroll
    for (int j = 0; j < 4; j++) {
        const __hip_bfloat162 lo =
            __float22bfloat162_rn(make_float2(acco[j][0] * inv, acco[j][1] * inv));
        const __hip_bfloat162 hi =
            __float22bfloat162_rn(make_float2(acco[j][2] * inv, acco[j][3] * inv));
        uint2 o = make_uint2(*(const unsigned int*)&lo, *(const unsigned int*)&hi);
        *(uint2*)&attn[orow + j * 16 + quad * 4] = o;
    }
}

// t-part: qc in [0,5): queries [0,288), keys/values kv-rows [72,216), L=144
// s-part: qc in [5,14): queries [288,864), keys/values kv-rows [0,72), L=72
// XCD swizzle: all 14 qc-blocks of an (h,b) on one XCD -> per-XCD KV working
// set 2.6MB < 4MB L2.
__global__ __launch_bounds__(256, 5) void attn_fused(const __hip_bfloat16* __restrict__ qb,
                                                     const __hip_bfloat16* __restrict__ kv,
                                                     __hip_bfloat16* __restrict__ attn) {
    __shared__ __align__(16) __hip_bfloat16 VTs[64 * 168];
    constexpr int NB = 14 * 12 * 32;  // 5376, % 8 == 0 -> bijective swizzle
    const int rid = (int)blockIdx.x + 14 * ((int)blockIdx.y + 12 * (int)blockIdx.z);
    const int vid = (rid & 7) * (NB / 8) + (rid >> 3);
    const int qc = vid % 14, g = vid / 14;
    const int h = g % 12, bq = g / 12;
    if (qc < 5)
        attn_part<144, 0, 72, 18, 5>(qb, kv, attn, qc, h, bq, VTs);
    else
        attn_part<72, 288, 0, 36, 3>(qb, kv, attn, qc - 5, h, bq, VTs);
}

// ---------------- launch ----------------
extern "C" void kernel_launch(void* const* d_in, const int* in_sizes, int n_in,
                              void* d_out, int out_size, void* d_ws, size_t ws_size,
                              hipStream_t stream) {
    const float* x     = (const float*)d_in[0];
    const float* Wqkv  = (const float*)d_in[1];
    const float* Wproj = (const float*)d_in[2];
    const float* bproj = (const float*)d_in[3];
    float* out = (float*)d_out;

    // workspace layout (bytes):
    //   [0, 42467328)            x_bf16  (27648 x 768)   -- later reused as attn
    //   [42467328, 46006272)     WqkvT   (2304 x 768)
    //   [46006272, 47185920)     WprojT  (768 x 768)
    //   [47185920, 89653248)     Qbuf    (27648 x 768)
    //   [89653248, 114819072)    KVbuf   (32 x 256 x 1536)
    char* ws = (char*)d_ws;
    __hip_bfloat16* xb     = (__hip_bfloat16*)ws;
    __hip_bfloat16* WqkvT  = (__hip_bfloat16*)(ws + 42467328);
    __hip_bfloat16* WprojT = (__hip_bfloat16*)(ws + 46006272);
    __hip_bfloat16* Qbuf   = (__hip_bfloat16*)(ws + 47185920);
    __hip_bfloat16* KVbuf  = (__hip_bfloat16*)(ws + 89653248);
    __hip_bfloat16* attn   = (__hip_bfloat16*)ws;  // alias xb: x consumed before attention

    prep_kernel<<<CVT_BLKS + TQKV_BLKS + TPROJ_BLKS, 256, 0, stream>>>(x, Wqkv, Wproj, xb,
                                                                       WqkvT, WprojT);
    gemm_qkv2<<<QKV_NWG, 256, 0, stream>>>(xb, WqkvT, Qbuf, KVbuf);
    attn_fused<<<dim3(14, Hh, Bb), 256, 0, stream>>>(Qbuf, KVbuf, attn);
    gemm_proj<<<dim3(Cc / 128, Mm / 128), 256, 0, stream>>>(attn, WprojT, out, bproj);
}

// Round 9
// 336.786 us; speedup vs baseline: 1.0700x; 1.0132x over previous
//
#include <hip/hip_runtime.h>
#include <hip/hip_bf16.h>

typedef __attribute__((ext_vector_type(8))) short short8;
typedef __attribute__((ext_vector_type(4))) float floatx4;

#define MFMA16(a, b, c) __builtin_amdgcn_mfma_f32_16x16x32_bf16((a), (b), (c), 0, 0, 0)

// Problem dims (fixed by setup_inputs)
static constexpr int Bb = 32, Nn = 864, Cc = 768, Hh = 12;
static constexpr int Mm = Bb * Nn;      // 27648
static constexpr int NKV = 2 * Cc;      // 1536 (K block then V block)
static constexpr int KVROWS = 256;      // padded KV rows per batch (216 used)

__device__ __forceinline__ void gload_lds16(const __hip_bfloat16* g, __hip_bfloat16* l) {
    __builtin_amdgcn_global_load_lds((const __attribute__((address_space(1))) void*)g,
                                     (__attribute__((address_space(3))) void*)l, 16, 0, 0);
}

// ---------------- fused prep: x cvt f32->bf16, W transposes+cvt ----------------
static constexpr int CVT_BLKS = (Mm * Cc / 4) / 256;             // 20736
static constexpr int TQKV_BLKS = (3 * Cc / 32) * (Cc / 32);      // 1728
static constexpr int TPROJ_BLKS = (Cc / 32) * (Cc / 32);         // 576

__global__ __launch_bounds__(256) void prep_kernel(const float* __restrict__ x,
                                                   const float* __restrict__ Wqkv,
                                                   const float* __restrict__ Wproj,
                                                   __hip_bfloat16* __restrict__ xb,
                                                   __hip_bfloat16* __restrict__ WqkvT,
                                                   __hip_bfloat16* __restrict__ WprojT) {
    __shared__ float tile[32][33];
    const int bx = blockIdx.x;
    if (bx < CVT_BLKS) {
        const int i = bx * 256 + threadIdx.x;
        const float4 v = ((const float4*)x)[i];
        __hip_bfloat16 o[4] = {__float2bfloat16(v.x), __float2bfloat16(v.y),
                               __float2bfloat16(v.z), __float2bfloat16(v.w)};
        ((uint2*)xb)[i] = *(const uint2*)o;
        return;
    }
    const float* in;
    __hip_bfloat16* out;
    int R, C, bid;
    if (bx < CVT_BLKS + TQKV_BLKS) {
        bid = bx - CVT_BLKS; in = Wqkv; out = WqkvT; R = Cc; C = 3 * Cc;
    } else {
        bid = bx - CVT_BLKS - TQKV_BLKS; in = Wproj; out = WprojT; R = Cc; C = Cc;
    }
    const int c0 = (bid % (C / 32)) * 32, r0 = (bid / (C / 32)) * 32;
    const int tx = threadIdx.x & 31, ty = threadIdx.x >> 5;
#pragma unroll
    for (int i = 0; i < 32; i += 8)
        tile[ty + i][tx] = in[(size_t)(r0 + ty + i) * C + c0 + tx];
    __syncthreads();
#pragma unroll
    for (int i = 0; i < 32; i += 8)
        out[(size_t)(c0 + ty + i) * R + r0 + tx] = __float2bfloat16(tile[tx][ty + i]);
}

// ---------------- fused Q+KV GEMM (measured 84us, m97-structure plateau) -------
static constexpr int QBLKS = 6 * (Mm / 128);             // 1296
static constexpr int KVBLKS = 12 * (Bb * KVROWS / 128);  // 768
static constexpr int QKV_NWG = QBLKS + KVBLKS;           // 2064, % 8 == 0

__global__ __launch_bounds__(256) void gemm_qkv2(const __hip_bfloat16* __restrict__ A,
                                                 const __hip_bfloat16* __restrict__ WqkvT,
                                                 __hip_bfloat16* __restrict__ Qbuf,
                                                 __hip_bfloat16* __restrict__ KVbuf) {
    __shared__ __align__(16) __hip_bfloat16 As[8192];  // panel s at s*4096, row*32+col
    __shared__ __align__(16) __hip_bfloat16 Bs[8192];

    const int braw = (int)blockIdx.x;
    const int sid = (braw & 7) * (QKV_NWG / 8) + (braw >> 3);  // bijective

    int arow0, orow0, btrow0, ncol0, Nout;
    __hip_bfloat16* Out;
    if (sid < QBLKS) {                 // Q: full M, N=768
        const int nt = sid % 6, mt = sid / 6;
        arow0 = mt * 128; orow0 = arow0;
        btrow0 = nt * 128; ncol0 = nt * 128;
        Out = Qbuf; Nout = Cc;
    } else {                           // K/V: rows [0,256) per batch, N=1536
        const int s = sid - QBLKS;
        const int nt = s % 12, mt = s / 12;
        const int bb = mt >> 1, keybase = (mt & 1) << 7;
        arow0 = bb * Nn + keybase;     // x rows [b*864, b*864+256)
        orow0 = bb * KVROWS + keybase; // packed per-batch KV rows
        btrow0 = Cc + nt * 128;        // WqkvT rows 768..2304 (K then V)
        ncol0 = nt * 128;
        Out = KVbuf; Nout = NKV;
    }

    const int t = threadIdx.x;
    const int lane = t & 63, wave = t >> 6;
    const int wm = (wave >> 1) * 64, wn = (wave & 1) * 64;
    const int ln = lane & 15, quad = lane >> 4;

    floatx4 acc[4][4] = {};

    const int r0 = t >> 2;          // 0..63
    const int cst = (t & 3) * 8;    // 0,8,16,24
    const __hip_bfloat16* Ag = A + (size_t)(arow0 + r0) * Cc + cst;
    const __hip_bfloat16* Bg = WqkvT + (size_t)(btrow0 + r0) * Cc + cst;
    const size_t rowskip = (size_t)64 * Cc;

    for (int k0 = 0; k0 < Cc; k0 += 64) {
        gload_lds16(Ag + k0,                &As[t * 8]);
        gload_lds16(Ag + k0 + rowskip,      &As[2048 + t * 8]);
        gload_lds16(Ag + k0 + 32,           &As[4096 + t * 8]);
        gload_lds16(Ag + k0 + 32 + rowskip, &As[6144 + t * 8]);
        gload_lds16(Bg + k0,                &Bs[t * 8]);
        gload_lds16(Bg + k0 + rowskip,      &Bs[2048 + t * 8]);
        gload_lds16(Bg + k0 + 32,           &Bs[4096 + t * 8]);
        gload_lds16(Bg + k0 + 32 + rowskip, &Bs[6144 + t * 8]);
        __syncthreads();

#pragma unroll
        for (int s = 0; s < 2; s++) {
            short8 af[4], bfr[4];
#pragma unroll
            for (int i = 0; i < 4; i++)
                af[i] = *(const short8*)&As[s * 4096 + (wm + i * 16 + ln) * 32 + quad * 8];
#pragma unroll
            for (int j = 0; j < 4; j++)
                bfr[j] = *(const short8*)&Bs[s * 4096 + (wn + j * 16 + ln) * 32 + quad * 8];
#pragma unroll
            for (int i = 0; i < 4; i++)
#pragma unroll
                for (int j = 0; j < 4; j++)
                    acc[i][j] = MFMA16(af[i], bfr[j], acc[i][j]);
        }
        __syncthreads();
    }

    // Epilogue. C/D layout: row = quad*4 + r, col = ln (verified m89/m91)
#pragma unroll
    for (int j = 0; j < 4; j++) {
        const int n = ncol0 + wn + j * 16 + ln;
#pragma unroll
        for (int i = 0; i < 4; i++) {
            const int mrow = orow0 + wm + i * 16 + quad * 4;
#pragma unroll
            for (int r = 0; r < 4; r++)
                Out[(size_t)(mrow + r) * Nout + n] = __float2bfloat16(acc[i][j][r]);
        }
    }
}

// ---------------- proj GEMM: C[M x 768] = A[M x 768] * BT^T + bias (f32 out) ---
__global__ __launch_bounds__(256) void gemm_proj(const __hip_bfloat16* __restrict__ A,
                                                 const __hip_bfloat16* __restrict__ BT,
                                                 float* __restrict__ Cout,
                                                 const float* __restrict__ bias) {
    __shared__ __align__(16) __hip_bfloat16 As[8192];
    __shared__ __align__(16) __hip_bfloat16 Bs[8192];
    const int gx = (int)gridDim.x;
    const int nwg = gx * (int)gridDim.y;
    const int braw = (int)blockIdx.y * gx + (int)blockIdx.x;
    const int sid = (braw & 7) * (nwg >> 3) + (braw >> 3);
    const int mt = sid / gx, nt = sid - mt * gx;
    const int m0 = mt << 7, n0 = nt * 128;
    const int t = threadIdx.x;
    const int lane = t & 63, wave = t >> 6;
    const int wm = (wave >> 1) * 64, wn = (wave & 1) * 64;
    const int ln = lane & 15, quad = lane >> 4;

    floatx4 acc[4][4] = {};
    const int r0 = t >> 2, cst = (t & 3) * 8;
    const __hip_bfloat16* Ag = A + (size_t)(m0 + r0) * Cc + cst;
    const __hip_bfloat16* Bg = BT + (size_t)(n0 + r0) * Cc + cst;
    const size_t rowskip = (size_t)64 * Cc;

    for (int k0 = 0; k0 < Cc; k0 += 64) {
        gload_lds16(Ag + k0,                &As[t * 8]);
        gload_lds16(Ag + k0 + rowskip,      &As[2048 + t * 8]);
        gload_lds16(Ag + k0 + 32,           &As[4096 + t * 8]);
        gload_lds16(Ag + k0 + 32 + rowskip, &As[6144 + t * 8]);
        gload_lds16(Bg + k0,                &Bs[t * 8]);
        gload_lds16(Bg + k0 + rowskip,      &Bs[2048 + t * 8]);
        gload_lds16(Bg + k0 + 32,           &Bs[4096 + t * 8]);
        gload_lds16(Bg + k0 + 32 + rowskip, &Bs[6144 + t * 8]);
        __syncthreads();
#pragma unroll
        for (int s = 0; s < 2; s++) {
            short8 af[4], bfr[4];
#pragma unroll
            for (int i = 0; i < 4; i++)
                af[i] = *(const short8*)&As[s * 4096 + (wm + i * 16 + ln) * 32 + quad * 8];
#pragma unroll
            for (int j = 0; j < 4; j++)
                bfr[j] = *(const short8*)&Bs[s * 4096 + (wn + j * 16 + ln) * 32 + quad * 8];
#pragma unroll
            for (int i = 0; i < 4; i++)
#pragma unroll
                for (int j = 0; j < 4; j++)
                    acc[i][j] = MFMA16(af[i], bfr[j], acc[i][j]);
        }
        __syncthreads();
    }
#pragma unroll
    for (int j = 0; j < 4; j++) {
        const int n = n0 + wn + j * 16 + ln;
        const float bv = bias[n];
#pragma unroll
        for (int i = 0; i < 4; i++) {
            const int mrow = m0 + wm + i * 16 + quad * 4;
#pragma unroll
            for (int r = 0; r < 4; r++)
                Cout[(size_t)(mrow + r) * Cc + n] = acc[i][j][r] + bv;
        }
    }
}

// ---------------- fused cross attention: r2 structure + 2-q-tile ILP per wave --
// Identical memory patterns to the measured 54.8us round-2 kernel (K direct from
// KVbuf, V LDS-staged with mod-add swizzle). NEW: each wave owns q-tile PAIR
// (2p, 2p+1): K fragment loads and V^T LDS reads are shared by two independent
// MFMA/exp/shuffle chains -> each chain's latency stalls are covered by the
// sibling, and blocks per (b,h) drop 14 -> 8 (V-stage work + residency rounds
// nearly halve).
template <int L, int QOFF, int KVOFF, int NQT, int NCH>
__device__ __forceinline__ void attn_pair(const __hip_bfloat16* __restrict__ qb,
                                          const __hip_bfloat16* __restrict__ kv,
                                          __hip_bfloat16* __restrict__ attn,
                                          int qc, int h, int b,
                                          __hip_bfloat16* VTs) {
    constexpr int KPAD = NCH * 32;               // padded key count for PV: t 160, s 96
    constexpr int VSTR = KPAD + 8;               // LDS stride for VT rows
    constexpr int NPAIR = NQT / 2;               // t 9, s 18
    const int t = threadIdx.x, lane = t & 63, wave = t >> 6;
    const int ln = lane & 15, quad = lane >> 4;
    const __hip_bfloat16 z16 = __float2bfloat16(0.0f);

    const __hip_bfloat16* kbase = kv + (size_t)(b * KVROWS + KVOFF) * NKV + h * 64;
    const __hip_bfloat16* vbase = kbase + Cc;   // V block at column offset 768

    // stage V transposed: VT[dd][key'], keys zero-padded to KPAD, swizzled cols
    for (int c = t; c < KPAD * 8; c += 256) {
        const int key = c >> 3, s8 = c & 7, d0 = s8 * 8;
        const int colp = (key + 8 * s8) % KPAD;   // dd>>3 == s8 for all 8 stores
        if (key < L) {
            uint4 raw = *(const uint4*)(vbase + (size_t)key * NKV + d0);
            const __hip_bfloat16* pv = (const __hip_bfloat16*)&raw;
#pragma unroll
            for (int jj = 0; jj < 8; jj++) VTs[(d0 + jj) * VSTR + colp] = pv[jj];
        } else {
#pragma unroll
            for (int jj = 0; jj < 8; jj++) VTs[(d0 + jj) * VSTR + colp] = z16;
        }
    }
    __syncthreads();

    const int pt = qc * 4 + wave;
    if (pt >= NPAIR) return;  // no further barriers below

    const int qt0 = 2 * pt;
    const __hip_bfloat16* qrowA =
        qb + (size_t)(b * Nn + QOFF + qt0 * 16 + ln) * Cc + h * 64;
    const __hip_bfloat16* qrowB = qrowA + (size_t)16 * Cc;
    const short8 aqA0 = *(const short8*)(qrowA + quad * 8);
    const short8 aqA1 = *(const short8*)(qrowA + 32 + quad * 8);
    const short8 aqB0 = *(const short8*)(qrowB + quad * 8);
    const short8 aqB1 = *(const short8*)(qrowB + 32 + quad * 8);

    float dsA = 0.0f, dsB = 0.0f;
    floatx4 accA[4] = {}, accB[4] = {};
    constexpr float CSC = 0.18033688011112042f;  // 0.125 * log2(e)

#pragma unroll
    for (int ch = 0; ch < NCH; ch++) {
        unsigned int pkA[2][2], pkB[2][2];
#pragma unroll
        for (int ti2 = 0; ti2 < 2; ti2++) {
            const int ti = ch * 2 + ti2;
            if (ti * 16 >= L) {  // fully-invalid tile (compile-time)
                pkA[ti2][0] = 0u; pkA[ti2][1] = 0u;
                pkB[ti2][0] = 0u; pkB[ti2][1] = 0u;
                continue;
            }
            const __hip_bfloat16* krow = kbase + (size_t)(ti * 16 + ln) * NKV;
            const short8 k0 = *(const short8*)(krow + quad * 8);
            const short8 k1 = *(const short8*)(krow + 32 + quad * 8);
            floatx4 sA = {0.f, 0.f, 0.f, 0.f}, sB = {0.f, 0.f, 0.f, 0.f};
            sA = MFMA16(k0, aqA0, sA);
            sA = MFMA16(k1, aqA1, sA);
            sB = MFMA16(k0, aqB0, sB);
            sB = MFMA16(k1, aqB1, sB);
            float pA[4], pB[4];
#pragma unroll
            for (int r = 0; r < 4; r++) {
                float eA = exp2f(sA[r] * CSC);
                float eB = exp2f(sB[r] * CSC);
                if (ti * 16 + 16 > L) {                           // partial tile
                    if (ti * 16 + quad * 4 + r >= L) { eA = 0.0f; eB = 0.0f; }
                }
                pA[r] = eA; dsA += eA;
                pB[r] = eB; dsB += eB;
            }
            {
                const __hip_bfloat162 lo = __float22bfloat162_rn(make_float2(pA[0], pA[1]));
                const __hip_bfloat162 hi = __float22bfloat162_rn(make_float2(pA[2], pA[3]));
                pkA[ti2][0] = *(const unsigned int*)&lo;
                pkA[ti2][1] = *(const unsigned int*)&hi;
            }
            {
                const __hip_bfloat162 lo = __float22bfloat162_rn(make_float2(pB[0], pB[1]));
                const __hip_bfloat162 hi = __float22bfloat162_rn(make_float2(pB[2], pB[3]));
                pkB[ti2][0] = *(const unsigned int*)&lo;
                pkB[ti2][1] = *(const unsigned int*)&hi;
            }
        }
        // Redistribute: target lane (ln, quad) needs tile (quad>>1), keys from
        // source quads 2*(quad&1) and 2*(quad&1)+1 (4 bf16 each).
        const int srcA = ln + ((quad & 1) << 5);
        const int srcB = srcA + 16;
        const bool hi2 = quad >= 2;
        union { unsigned int u[4]; short8 v; } pfA, pfB;
        {
            const unsigned int c0 = (unsigned int)__shfl((int)pkA[0][0], srcA);
            const unsigned int c1 = (unsigned int)__shfl((int)pkA[0][1], srcA);
            const unsigned int c2 = (unsigned int)__shfl((int)pkA[0][0], srcB);
            const unsigned int c3 = (unsigned int)__shfl((int)pkA[0][1], srcB);
            const unsigned int d0 = (unsigned int)__shfl((int)pkA[1][0], srcA);
            const unsigned int d1 = (unsigned int)__shfl((int)pkA[1][1], srcA);
            const unsigned int d2 = (unsigned int)__shfl((int)pkA[1][0], srcB);
            const unsigned int d3 = (unsigned int)__shfl((int)pkA[1][1], srcB);
            pfA.u[0] = hi2 ? d0 : c0;
            pfA.u[1] = hi2 ? d1 : c1;
            pfA.u[2] = hi2 ? d2 : c2;
            pfA.u[3] = hi2 ? d3 : c3;
        }
        {
            const unsigned int c0 = (unsigned int)__shfl((int)pkB[0][0], srcA);
            const unsigned int c1 = (unsigned int)__shfl((int)pkB[0][1], srcA);
            const unsigned int c2 = (unsigned int)__shfl((int)pkB[0][0], srcB);
            const unsigned int c3 = (unsigned int)__shfl((int)pkB[0][1], srcB);
            const unsigned int d0 = (unsigned int)__shfl((int)pkB[1][0], srcA);
            const unsigned int d1 = (unsigned int)__shfl((int)pkB[1][1], srcA);
            const unsigned int d2 = (unsigned int)__shfl((int)pkB[1][0], srcB);
            const unsigned int d3 = (unsigned int)__shfl((int)pkB[1][1], srcB);
            pfB.u[0] = hi2 ? d0 : c0;
            pfB.u[1] = hi2 ? d1 : c1;
            pfB.u[2] = hi2 ? d2 : c2;
            pfB.u[3] = hi2 ? d3 : c3;
        }
        // O^T accumulate: lane holds O^T[dd = j*16 + quad*4 + r][q = ln].
        // V^T fragment shared by both chains (swizzled col, same as r2).
#pragma unroll
        for (int j = 0; j < 4; j++) {
            const int dd = j * 16 + ln;
            const int colp = (ch * 32 + quad * 8 + ((dd >> 3) << 3)) % KPAD;
            const short8 vt = *(const short8*)&VTs[dd * VSTR + colp];
            accA[j] = MFMA16(vt, pfA.v, accA[j]);
            accB[j] = MFMA16(vt, pfB.v, accB[j]);
        }
    }

    // Denominator: per-lane partials cover keys {quad*4+r over all tiles}, col q=ln.
    dsA += __shfl_xor(dsA, 16); dsA += __shfl_xor(dsA, 32);
    dsB += __shfl_xor(dsB, 16); dsB += __shfl_xor(dsB, 32);
    const float invA = 1.0f / dsA, invB = 1.0f / dsB;

    const size_t orowA = (size_t)(b * Nn + QOFF + qt0 * 16 + ln) * Cc + h * 64;
    const size_t orowB = orowA + (size_t)16 * Cc;
#pragma unroll
    for (int j = 0; j < 4; j++) {
        {
            const __hip_bfloat162 lo =
                __float22bfloat162_rn(make_float2(accA[j][0] * invA, accA[j][1] * invA));
            const __hip_bfloat162 hi =
                __float22bfloat162_rn(make_float2(accA[j][2] * invA, accA[j][3] * invA));
            uint2 o = make_uint2(*(const unsigned int*)&lo, *(const unsigned int*)&hi);
            *(uint2*)&attn[orowA + j * 16 + quad * 4] = o;
        }
        {
            const __hip_bfloat162 lo =
                __float22bfloat162_rn(make_float2(accB[j][0] * invB, accB[j][1] * invB));
            const __hip_bfloat162 hi =
                __float22bfloat162_rn(make_float2(accB[j][2] * invB, accB[j][3] * invB));
            uint2 o = make_uint2(*(const unsigned int*)&lo, *(const unsigned int*)&hi);
            *(uint2*)&attn[orowB + j * 16 + quad * 4] = o;
        }
    }
}

// 8 blocks per (b,h): qc in [0,3) = t-part (9 pairs over 12 wave-slots),
// qc in [3,8) = s-part (18 pairs over 20 wave-slots). 3072 blocks, % 8 == 0.
// XCD swizzle keeps one (b,h)'s blocks on one XCD (K/V L2 reuse).
static constexpr int ATTN_NB = 8 * Hh * Bb;  // 3072

__global__ __launch_bounds__(256, 4) void attn_fused(const __hip_bfloat16* __restrict__ qb,
                                                     const __hip_bfloat16* __restrict__ kv,
                                                     __hip_bfloat16* __restrict__ attn) {
    __shared__ __align__(16) __hip_bfloat16 VTs[64 * 168];
    const int rid = (int)blockIdx.x + 8 * ((int)blockIdx.y + 12 * (int)blockIdx.z);
    const int vid = (rid & 7) * (ATTN_NB / 8) + (rid >> 3);
    const int qc = vid % 8, g = vid / 8;
    const int h = g % 12, bq = g / 12;
    if (qc < 3)
        attn_pair<144, 0, 72, 18, 5>(qb, kv, attn, qc, h, bq, VTs);
    else
        attn_pair<72, 288, 0, 36, 3>(qb, kv, attn, qc - 3, h, bq, VTs);
}

// ---------------- launch ----------------
extern "C" void kernel_launch(void* const* d_in, const int* in_sizes, int n_in,
                              void* d_out, int out_size, void* d_ws, size_t ws_size,
                              hipStream_t stream) {
    const float* x     = (const float*)d_in[0];
    const float* Wqkv  = (const float*)d_in[1];
    const float* Wproj = (const float*)d_in[2];
    const float* bproj = (const float*)d_in[3];
    float* out = (float*)d_out;

    // workspace layout (bytes):
    //   [0, 42467328)            x_bf16  (27648 x 768)   -- later reused as attn
    //   [42467328, 46006272)     WqkvT   (2304 x 768)
    //   [46006272, 47185920)     WprojT  (768 x 768)
    //   [47185920, 89653248)     Qbuf    (27648 x 768)
    //   [89653248, 114819072)    KVbuf   (32 x 256 x 1536)
    char* ws = (char*)d_ws;
    __hip_bfloat16* xb     = (__hip_bfloat16*)ws;
    __hip_bfloat16* WqkvT  = (__hip_bfloat16*)(ws + 42467328);
    __hip_bfloat16* WprojT = (__hip_bfloat16*)(ws + 46006272);
    __hip_bfloat16* Qbuf   = (__hip_bfloat16*)(ws + 47185920);
    __hip_bfloat16* KVbuf  = (__hip_bfloat16*)(ws + 89653248);
    __hip_bfloat16* attn   = (__hip_bfloat16*)ws;  // alias xb: x consumed before attention

    prep_kernel<<<CVT_BLKS + TQKV_BLKS + TPROJ_BLKS, 256, 0, stream>>>(x, Wqkv, Wproj, xb,
                                                                       WqkvT, WprojT);
    gemm_qkv2<<<QKV_NWG, 256, 0, stream>>>(xb, WqkvT, Qbuf, KVbuf);
    attn_fused<<<dim3(8, Hh, Bb), 256, 0, stream>>>(Qbuf, KVbuf, attn);
    gemm_proj<<<dim3(Cc / 128, Mm / 128), 256, 0, stream>>>(attn, WprojT, out, bproj);
}